// Round 19
// baseline (263.080 us; speedup 1.0000x reference)
//
#include <hip/hip_runtime.h>
#include <math.h>

typedef __bf16 bf16;
typedef __attribute__((ext_vector_type(8))) __bf16 bf16x8;
typedef __attribute__((ext_vector_type(4))) float f32x4;

#define MFMA16(a, b, c) __builtin_amdgcn_mfma_f32_16x16x32_bf16(a, b, c, 0, 0, 0)

__device__ __forceinline__ void gld_lds16(const void* g, void* l) {
  __builtin_amdgcn_global_load_lds(
      (const __attribute__((address_space(1))) unsigned int*)g,
      (__attribute__((address_space(3))) unsigned int*)l, 16, 0, 0);
}

// ---------------- fused pre-pass: conv(x->bf16) | frag-pack W_pos/W_qkv/W_out | pe_proj
// BP layout: element (k,c) -> BP[((c>>4)*(K>>3) + (k>>3))*128 + (c&15)*8 + (k&7)]
__global__ __launch_bounds__(256) void prep_kernel(
    const float* __restrict__ x, const float* __restrict__ W_pos,
    const float* __restrict__ W_qkv, const float* __restrict__ W_out,
    const float* __restrict__ pe,
    bf16* __restrict__ x_bf, bf16* __restrict__ wpos_p, bf16* __restrict__ wqkv_p,
    bf16* __restrict__ wout_p, bf16* __restrict__ pe_pj) {
  __shared__ float tile[32][33];
  const int tid = threadIdx.x;
  int blk = blockIdx.x;
  if (blk < 4096) {  // x -> bf16
    int idx = blk * 256 + tid;
    const float4 a = ((const float4*)x)[idx * 2];
    const float4 b = ((const float4*)x)[idx * 2 + 1];
    bf16x8 o = {(bf16)a.x, (bf16)a.y, (bf16)a.z, (bf16)a.w,
                (bf16)b.x, (bf16)b.y, (bf16)b.z, (bf16)b.w};
    *(bf16x8*)(x_bf + (size_t)idx * 8) = o;
    return;
  }
  blk -= 4096;
  if (blk < 4096) {  // W[K][N] -> BP fragment-major bf16
    const float* W; bf16* BP; int K, N, bx, by;
    if (blk < 1024)      { W = W_pos; BP = wpos_p; K = 1024; N = 1024; bx = blk & 31; by = blk >> 5; }
    else if (blk < 3584) { int b2 = blk - 1024; W = W_qkv; BP = wqkv_p; K = 1024; N = 2560; bx = b2 % 80; by = b2 / 80; }
    else                 { int b2 = blk - 3584; W = W_out; BP = wout_p; K = 512;  N = 1024; bx = b2 & 31; by = b2 >> 5; }
    const int n0 = bx * 32, k0 = by * 32;
    const int tx = tid & 31, ty = tid >> 5;
#pragma unroll
    for (int i = 0; i < 4; ++i)
      tile[ty + 8 * i][tx] = W[(size_t)(k0 + ty + 8 * i) * N + n0 + tx];
    __syncthreads();
    if (tid < 128) {
      int cc = tid & 31, kq = tid >> 5;
      int c = n0 + cc, k = k0 + kq * 8;
      bf16x8 v;
#pragma unroll
      for (int i = 0; i < 8; ++i) v[i] = (bf16)tile[kq * 8 + i][cc];
      *(bf16x8*)(BP + ((size_t)(c >> 4) * (K >> 3) + (k >> 3)) * 128 + (c & 15) * 8) = v;
    }
    return;
  }
  blk -= 4096;  // pe_proj
  int idx = blk * 256 + tid;
  int n = idx >> 10, c = idx & 1023;
  float s = 0.f;
#pragma unroll
  for (int e = 0; e < 32; ++e)
    s += pe[n * 32 + e] * W_pos[(size_t)(1024 + e) * 1024 + c];
  pe_pj[idx] = (bf16)s;
}

// ---------------- bf16 MFMA GEMM, B-direct, m97 geometry (r15/r18 proven; GEMM1/3)
template <int NT, int OUT_BF16>
__global__ __launch_bounds__(256, 3) void gemm_bd(
    const bf16* __restrict__ A, const bf16* __restrict__ BP, void* __restrict__ Cout,
    int M, int N, int K,
    const float* __restrict__ bias, const bf16* __restrict__ add_full,
    const bf16* __restrict__ add_mod) {
  __shared__ __align__(16) bf16 As[3][128 * 64];  // 16KB per buffer
  const int tid = threadIdx.x;
  const int wave = tid >> 6, lane = tid & 63;
  const int wr = wave >> 1, wc = wave & 1;
  const int lr = lane & 15, lg = lane >> 4;
  const int KB = K >> 3;

  const int nwg = gridDim.x * gridDim.y;
  const int bid = blockIdx.y * gridDim.x + blockIdx.x;
  const int s = (bid & 7) * (nwg >> 3) + (bid >> 3);
  const int row0 = (s / gridDim.x) * 128, col0 = (s % gridDim.x) * 128;
  const int cb0 = (col0 >> 4) + wc * 4;

  const int trow = tid >> 3;
  const int cbd = ((tid & 7) * 16) ^ ((trow & 7) << 4);
  const bf16* asrc = A + (size_t)(row0 + trow) * K + (cbd >> 1);
  f32x4 acc[4][4] = {};

  auto STAGE = [&](int sel, int t) {
    char* al = (char*)&As[sel][0] + tid * 16;
#pragma unroll
    for (int c = 0; c < 4; ++c)
      gld_lds16(asrc + (size_t)c * 32 * K + t * 64, al + c * 4096);
  };

  STAGE(0, 0);
  STAGE(1, 1);
  asm volatile("s_waitcnt vmcnt(4)" ::: "memory");
  __builtin_amdgcn_s_barrier();

#pragma unroll
  for (int t = 0; t < NT; ++t) {
    if (t + 2 < NT) STAGE((t + 2) % 3, t + 2);
    const char* Ab = (const char*)&As[t % 3][0];
#pragma unroll
    for (int kc = 0; kc < 2; ++kc) {
      const int kb = (t << 3) + kc * 4 + lg;
      bf16x8 bfr[4], af[4];
#pragma unroll
      for (int nt = 0; nt < 4; ++nt)
        bfr[nt] = *(const bf16x8*)(BP + ((size_t)(cb0 + nt) * KB + kb) * 128 + lr * 8);
#pragma unroll
      for (int mt = 0; mt < 4; ++mt) {
        int r = wr * 64 + mt * 16 + lr;
        af[mt] = *(const bf16x8*)(Ab + r * 128 + ((kc * 64 + lg * 16) ^ ((r & 7) << 4)));
      }
      __builtin_amdgcn_s_setprio(1);
#pragma unroll
      for (int mt = 0; mt < 4; ++mt)
#pragma unroll
        for (int nt = 0; nt < 4; ++nt)
          acc[mt][nt] = MFMA16(af[mt], bfr[nt], acc[mt][nt]);
      __builtin_amdgcn_s_setprio(0);
    }
    if (t + 2 < NT)
      asm volatile("s_waitcnt vmcnt(4)" ::: "memory");
    else
      asm volatile("s_waitcnt vmcnt(0)" ::: "memory");
    __builtin_amdgcn_s_barrier();
  }

#pragma unroll
  for (int mt = 0; mt < 4; ++mt) {
#pragma unroll
    for (int v = 0; v < 4; ++v) {
      int r = row0 + wr * 64 + mt * 16 + lg * 4 + v;
#pragma unroll
      for (int nt = 0; nt < 4; ++nt) {
        int c = col0 + wc * 64 + nt * 16 + lr;
        float val = acc[mt][nt][v];
        if (bias) val += bias[c];
        if (add_full) val += (float)add_full[(size_t)r * N + c];
        if (add_mod) val += (float)add_mod[(size_t)(r & 1023) * N + c];
        if (OUT_BF16)
          ((bf16*)Cout)[(size_t)r * N + c] = (bf16)val;
        else
          ((float*)Cout)[(size_t)r * N + c] = val;
      }
    }
  }
}

// ---------------- zero-LDS fragment-direct GEMM (GEMM2): both A and B fragment-packed
// in global; no LDS, no barriers; occupancy-driven latency hiding (4 blocks/CU).
// AP layout == BP layout: ((r>>4)*KB + (k>>3))*128 + (r&15)*8 + (k&7).
__global__ __launch_bounds__(256, 4) void gemm_ff(
    const bf16* __restrict__ AP, const bf16* __restrict__ BP, bf16* __restrict__ Cout,
    int M, int N, int K, const float* __restrict__ bias) {
  const int tid = threadIdx.x;
  const int wave = tid >> 6, lane = tid & 63;
  const int wr = wave >> 1, wc = wave & 1;
  const int lr = lane & 15, lg = lane >> 4;
  const int KB = K >> 3;

  const int nwg = gridDim.x * gridDim.y;
  const int bid = blockIdx.y * gridDim.x + blockIdx.x;
  const int s = (bid & 7) * (nwg >> 3) + (bid >> 3);
  const int row0 = (s / gridDim.x) * 128, col0 = (s % gridDim.x) * 128;
  const int rb0 = (row0 >> 4) + wr * 4;
  const int cb0 = (col0 >> 4) + wc * 4;

  const bf16* ap = AP + (size_t)rb0 * KB * 128 + lr * 8;
  const bf16* bp = BP + (size_t)cb0 * KB * 128 + lr * 8;
  f32x4 acc[4][4] = {};

#pragma unroll 4
  for (int kk = 0; kk < 32; ++kk) {  // K/32 MFMA steps; kb = kk*4 + lg
    const int kb = kk * 4 + lg;
    bf16x8 af[4], bfr[4];
#pragma unroll
    for (int mt = 0; mt < 4; ++mt)
      af[mt] = *(const bf16x8*)(ap + ((size_t)mt * KB + kb) * 128);
#pragma unroll
    for (int nt = 0; nt < 4; ++nt)
      bfr[nt] = *(const bf16x8*)(bp + ((size_t)nt * KB + kb) * 128);
#pragma unroll
    for (int mt = 0; mt < 4; ++mt)
#pragma unroll
      for (int nt = 0; nt < 4; ++nt)
        acc[mt][nt] = MFMA16(af[mt], bfr[nt], acc[mt][nt]);
  }

#pragma unroll
  for (int mt = 0; mt < 4; ++mt) {
#pragma unroll
    for (int v = 0; v < 4; ++v) {
      int r = row0 + wr * 64 + mt * 16 + lg * 4 + v;
#pragma unroll
      for (int nt = 0; nt < 4; ++nt) {
        int c = col0 + wc * 64 + nt * 16 + lr;
        Cout[(size_t)r * N + c] = (bf16)(acc[mt][nt][v] + bias[c]);
      }
    }
  }
}

// ---------------- FeatureNorm over sequence dim; h bf16 in, hn written FRAGMENT-PACKED
// (AP layout for gemm_ff). Apply phase: thread owns (row, d-octet) -> 16B packed store;
// wave = 8 octets x 8 rows -> 128B-contiguous chunks.
__global__ __launch_bounds__(512) void featnorm_kernel(const bf16* __restrict__ h,
                                                       bf16* __restrict__ hnp,
                                                       const float* __restrict__ gamma,
                                                       const float* __restrict__ beta) {
  const int b = blockIdx.x >> 4;
  const int d0 = (blockIdx.x & 15) << 6;
  const int tid = threadIdx.x;
  const int c = tid & 63, g = tid >> 6;
  const size_t base = (size_t)b * (1024 * 1024) + d0 + c;
  float s = 0.f, s2 = 0.f;
  for (int n = g * 128; n < g * 128 + 128; ++n) {
    float v = (float)h[base + (size_t)n * 1024];
    s += v; s2 += v * v;
  }
  __shared__ float rs[8][64], rs2[8][64];
  rs[g][c] = s; rs2[g][c] = s2;
  __syncthreads();
  __shared__ float smean[64], srstd[64];
  if (tid < 64) {
    float S = 0.f, S2 = 0.f;
#pragma unroll
    for (int q = 0; q < 8; ++q) { S += rs[q][tid]; S2 += rs2[q][tid]; }
    float mean = S * (1.f / 1024.f);
    float var = S2 * (1.f / 1024.f) - mean * mean;
    smean[tid] = mean;
    srstd[tid] = rsqrtf(var + 1e-5f);
  }
  __syncthreads();

  // apply + packed write: oct = d-octet (0..7), slot = row slot (0..63)
  const int oct = tid & 7, slot = tid >> 3;
  float mean8[8], rstd8[8], gm8[8], bt8[8];
#pragma unroll
  for (int j = 0; j < 8; ++j) {
    int dl = oct * 8 + j;
    mean8[j] = smean[dl]; rstd8[j] = srstd[dl];
    gm8[j] = gamma[d0 + dl]; bt8[j] = beta[d0 + dl];
  }
  for (int it = 0; it < 16; ++it) {
    int n = it * 64 + slot;
    size_t r = (size_t)b * 1024 + n;
    bf16x8 hv = *(const bf16x8*)(h + r * 1024 + d0 + oct * 8);
    bf16x8 ov;
#pragma unroll
    for (int j = 0; j < 8; ++j)
      ov[j] = (bf16)(gm8[j] * ((float)hv[j] - mean8[j]) * rstd8[j] + bt8[j]);
    *(bf16x8*)(hnp + ((r >> 4) * 128 + (d0 >> 3) + oct) * 128 + (r & 15) * 8) = ov;
  }
}

// ---------------- fused sk (log2-domain k norms) + vtrans
__global__ __launch_bounds__(256) void skvt_kernel(const bf16* __restrict__ qkv,
                                                   const float* __restrict__ scale_ptr,
                                                   float* __restrict__ skl,
                                                   bf16* __restrict__ vT) {
  const int tid = threadIdx.x;
  if (blockIdx.x < 4096) {
    const int lr = tid & 15;
    const int task = blockIdx.x * 16 + (tid >> 4);
    const int bh = task >> 10, n = task & 1023;
    const int b = bh >> 3, h = bh & 7;
    const bf16x8 v = *(const bf16x8*)(qkv + (size_t)(b * 1024 + n) * 2560 +
                                      1024 + h * 128 + lr * 8);
    float s = 0.f;
#pragma unroll
    for (int i = 0; i < 8; ++i) { float f = (float)v[i]; s += f * f; }
#pragma unroll
    for (int off = 1; off < 16; off <<= 1) s += __shfl_xor(s, off);
    if (lr == 0) {
      float sc = scale_ptr[0];
      skl[task] = s * (1.44269504f / (sc * sc));
    }
    return;
  }
  __shared__ bf16 tile[32][34];
  const int blk = blockIdx.x - 4096;
  const int b = blk >> 9;
  const int rem = blk & 511;
  const int c0 = (rem >> 5) * 32, n0 = (rem & 31) * 32;
  const int tx = tid & 31, ty = tid >> 5;
#pragma unroll
  for (int i = 0; i < 4; ++i)
    tile[ty + 8 * i][tx] = qkv[(size_t)(b * 1024 + n0 + ty + 8 * i) * 2560 + 2048 + c0 + tx];
  __syncthreads();
#pragma unroll
  for (int i = 0; i < 4; ++i)
    vT[(size_t)(b * 512 + c0 + ty + 8 * i) * 1024 + n0 + tx] = tile[tx][ty + 8 * i];
}

// ---------------- MFMA distance attention, QBLK=128 (8 waves, 512 thr).
// r11 2-buffer version (68KB LDS -> 2 blocks/CU; cross-block overlap hides drains).
__global__ __launch_bounds__(512, 4) void attn_mfma(const bf16* __restrict__ qkv,
                                                    const bf16* __restrict__ vT,
                                                    const float* __restrict__ skl,
                                                    const float* __restrict__ scale_ptr,
                                                    bf16* __restrict__ attn_o) {
  const int swz = ((blockIdx.x & 7) << 6) + (blockIdx.x >> 3);
  const int it = swz & 7, bh = swz >> 3;
  const int b = bh >> 3, h = bh & 7;
  const int i0 = it * 128;
  const int tid = threadIdx.x, wave = tid >> 6, lane = tid & 63;
  const int lr = lane & 15, lg = lane >> 4;
  const float sc = scale_ptr[0];
  const float c2 = 2.f * 1.44269504f / (sc * sc);

  __shared__ __align__(16) bf16 Ks[2][64 * 128];
  __shared__ __align__(16) bf16 Vs[2][64 * 64];
  __shared__ __align__(16) bf16 Ps[8][16 * 64];
  __shared__ float sks[1024];

  const int trowK = tid >> 4;
  const int cbKd = ((tid & 15) * 16) ^ ((trowK & 7) << 4);
  const bf16* ksrc = qkv + (size_t)(b * 1024 + trowK) * 2560 + 1024 + h * 128 + (cbKd >> 1);
  const int trowV = tid >> 3;
  const int cbVd = ((tid & 7) * 16) ^ ((trowV & 7) << 4);
  const bf16* vsrc = vT + (size_t)(b * 512 + h * 64 + trowV) * 1024 + (cbVd >> 1);

  auto STAGE = [&](int sel, int jt) {
    const bf16* kp = ksrc + (size_t)jt * 64 * 2560;
    char* kl = (char*)&Ks[sel][0] + tid * 16;
    gld_lds16(kp, kl);
    gld_lds16(kp + (size_t)32 * 2560, kl + 8192);
    gld_lds16(vsrc + jt * 64, (char*)&Vs[sel][0] + tid * 16);
  };

  {
    float2 sv = ((const float2*)(skl + (size_t)bh * 1024))[tid];
    *(float2*)&sks[tid * 2] = sv;
  }
  bf16x8 qf[4];
  {
    const bf16* qrow = qkv + (size_t)(b * 1024 + i0 + wave * 16 + lr) * 2560 + h * 128;
#pragma unroll
    for (int kc = 0; kc < 4; ++kc) qf[kc] = *(const bf16x8*)(qrow + kc * 32 + lg * 8);
  }
  __syncthreads();

  bf16x8 vones;
  {
    bf16 one_or_zero = (lr == 0) ? (bf16)1.0f : (bf16)0.0f;
#pragma unroll
    for (int i = 0; i < 8; ++i) vones[i] = one_or_zero;
  }

  f32x4 o[4] = {};
  f32x4 o_l = {};

  STAGE(0, 0);
  asm volatile("s_waitcnt vmcnt(0)" ::: "memory");
  __builtin_amdgcn_s_barrier();

#pragma unroll
  for (int jt = 0; jt < 16; ++jt) {
    const int cur = jt & 1;
    if (jt < 15) STAGE(cur ^ 1, jt + 1);

    f32x4 sacc[4] = {};
    __builtin_amdgcn_s_setprio(1);
#pragma unroll
    for (int kc = 0; kc < 4; ++kc) {
#pragma unroll
      for (int nt = 0; nt < 4; ++nt) {
        int j = nt * 16 + lr;
        int byte = j * 256 + (((kc * 32 + lg * 8) * 2) ^ ((j & 7) << 4));
        bf16x8 kf = *(const bf16x8*)((const char*)&Ks[cur][0] + byte);
        sacc[nt] = MFMA16(qf[kc], kf, sacc[nt]);
      }
    }
    __builtin_amdgcn_s_setprio(0);

#pragma unroll
    for (int nt = 0; nt < 4; ++nt) {
      float skv = sks[jt * 64 + nt * 16 + lr];
#pragma unroll
      for (int v = 0; v < 4; ++v) {
        float p = __builtin_amdgcn_exp2f(sacc[nt][v] * c2 - skv);
        int r = lg * 4 + v, c = nt * 16 + lr;
        int byte = r * 128 + ((c * 2) ^ ((r & 7) << 4));
        *(bf16*)((char*)&Ps[wave][0] + byte) = (bf16)p;
      }
    }
    bf16x8 pf[2];
#pragma unroll
    for (int kc = 0; kc < 2; ++kc) {
      int byte = lr * 128 + (((kc * 32 + lg * 8) * 2) ^ ((lr & 7) << 4));
      pf[kc] = *(const bf16x8*)((const char*)&Ps[wave][0] + byte);
    }
    __builtin_amdgcn_s_setprio(1);
#pragma unroll
    for (int kc = 0; kc < 2; ++kc) {
#pragma unroll
      for (int nt = 0; nt < 4; ++nt) {
        int d = nt * 16 + lr;
        int byte = d * 128 + (((kc * 32 + lg * 8) * 2) ^ ((d & 7) << 4));
        bf16x8 vf = *(const bf16x8*)((const char*)&Vs[cur][0] + byte);
        o[nt] = MFMA16(pf[kc], vf, o[nt]);
      }
      o_l = MFMA16(pf[kc], vones, o_l);
    }
    __builtin_amdgcn_s_setprio(0);

    asm volatile("s_waitcnt vmcnt(0)" ::: "memory");
    __builtin_amdgcn_s_barrier();
  }

#pragma unroll
  for (int v = 0; v < 4; ++v) {
    float ls = __shfl(o_l[v], lg << 4);
    float inv = 1.f / ls;
    int r = i0 + wave * 16 + lg * 4 + v;
#pragma unroll
    for (int nt = 0; nt < 4; ++nt) {
      int c = h * 64 + nt * 16 + lr;
      attn_o[(size_t)(b * 1024 + r) * 512 + c] = (bf16)(o[nt][v] * inv);
    }
  }
}

extern "C" void kernel_launch(void* const* d_in, const int* in_sizes, int n_in,
                              void* d_out, int out_size, void* d_ws, size_t ws_size,
                              hipStream_t stream) {
  const float* x     = (const float*)d_in[0];
  const float* gamma = (const float*)d_in[1];
  const float* beta  = (const float*)d_in[2];
  const float* pe    = (const float*)d_in[3];
  const float* W_pos = (const float*)d_in[4];
  const float* b_pos = (const float*)d_in[5];
  const float* W_qkv = (const float*)d_in[6];
  const float* b_qkv = (const float*)d_in[7];
  const float* W_out = (const float*)d_in[8];
  const float* b_out = (const float*)d_in[9];
  const float* scale = (const float*)d_in[10];
  float* outp = (float*)d_out;

  char* ws = (char*)d_ws;
  const size_t MB = 1 << 20;
  bf16* x_bf   = (bf16*)(ws);            // 16MB, persists to GEMM3 (bf16 residual)
  bf16* wpos_p = (bf16*)(ws + 16 * MB);  // 2MB  (fragment-packed)
  bf16* wqkv_p = (bf16*)(ws + 18 * MB);  // 5MB  (fragment-packed)
  bf16* wout_p = (bf16*)(ws + 23 * MB);  // 1MB  (fragment-packed)
  bf16* pe_pj  = (bf16*)(ws + 24 * MB);  // 2MB (dead after GEMM1)
  bf16* vT     = (bf16*)(ws + 24 * MB);  // 8MB (aliases pe_pj region)
  bf16* h      = (bf16*)(ws + 32 * MB);  // 16MB (dead after featnorm)
  bf16* attn_o = (bf16*)(ws + 32 * MB);  // 8MB (aliases h)
  bf16* qkv    = (bf16*)(ws + 48 * MB);  // 40MB
  float* skl   = (float*)(ws + 88 * MB); // 256KB
  bf16* hnp    = (bf16*)(ws + 96 * MB);  // 16MB (fragment-packed hn)

  prep_kernel<<<12288, 256, 0, stream>>>(x, W_pos, W_qkv, W_out, pe,
                                         x_bf, wpos_p, wqkv_p, wout_p, pe_pj);
  // h = x + x@W_pos + pe_pj + b_pos   (bf16 out, bf16 residual) — 512 blocks
  gemm_bd<16, 1><<<dim3(8, 64), 256, 0, stream>>>(x_bf, wpos_p, h, 8192, 1024, 1024,
                                                  b_pos, x_bf, pe_pj);
  featnorm_kernel<<<128, 512, 0, stream>>>(h, hnp, gamma, beta);
  // qkv = hn @ W_qkv + b_qkv  (bf16 out) — zero-LDS fragment-direct, 1280 blocks
  gemm_ff<<<dim3(20, 64), 256, 0, stream>>>(hnp, wqkv_p, qkv, 8192, 2560, 1024, b_qkv);
  skvt_kernel<<<8192, 256, 0, stream>>>(qkv, scale, skl, vT);
  attn_mfma<<<512, 512, 0, stream>>>(qkv, vT, skl, scale, attn_o);
  // out = x + attn_o @ W_out + b_out  (fp32 out, bf16 residual) — 512 blocks
  gemm_bd<8, 0><<<dim3(8, 64), 256, 0, stream>>>(attn_o, wout_p, outp, 8192, 1024, 512,
                                                 b_out, x_bf, nullptr);
}

// Round 20
// 243.545 us; speedup vs baseline: 1.0802x; 1.0802x over previous
//
#include <hip/hip_runtime.h>
#include <math.h>

typedef __bf16 bf16;
typedef __attribute__((ext_vector_type(8))) __bf16 bf16x8;
typedef __attribute__((ext_vector_type(4))) float f32x4;

#define MFMA16(a, b, c) __builtin_amdgcn_mfma_f32_16x16x32_bf16(a, b, c, 0, 0, 0)

__device__ __forceinline__ void gld_lds16(const void* g, void* l) {
  __builtin_amdgcn_global_load_lds(
      (const __attribute__((address_space(1))) unsigned int*)g,
      (__attribute__((address_space(3))) unsigned int*)l, 16, 0, 0);
}

// ---------------- fused pre-pass: conv(x->bf16) | frag-pack W_pos/W_qkv/W_out | pe_proj
// BP layout: element (k,c) -> BP[((c>>4)*(K>>3) + (k>>3))*128 + (c&15)*8 + (k&7)]
__global__ __launch_bounds__(256) void prep_kernel(
    const float* __restrict__ x, const float* __restrict__ W_pos,
    const float* __restrict__ W_qkv, const float* __restrict__ W_out,
    const float* __restrict__ pe,
    bf16* __restrict__ x_bf, bf16* __restrict__ wpos_p, bf16* __restrict__ wqkv_p,
    bf16* __restrict__ wout_p, bf16* __restrict__ pe_pj) {
  __shared__ float tile[32][33];
  const int tid = threadIdx.x;
  int blk = blockIdx.x;
  if (blk < 4096) {  // x -> bf16
    int idx = blk * 256 + tid;
    const float4 a = ((const float4*)x)[idx * 2];
    const float4 b = ((const float4*)x)[idx * 2 + 1];
    bf16x8 o = {(bf16)a.x, (bf16)a.y, (bf16)a.z, (bf16)a.w,
                (bf16)b.x, (bf16)b.y, (bf16)b.z, (bf16)b.w};
    *(bf16x8*)(x_bf + (size_t)idx * 8) = o;
    return;
  }
  blk -= 4096;
  if (blk < 4096) {  // W[K][N] -> BP fragment-major bf16
    const float* W; bf16* BP; int K, N, bx, by;
    if (blk < 1024)      { W = W_pos; BP = wpos_p; K = 1024; N = 1024; bx = blk & 31; by = blk >> 5; }
    else if (blk < 3584) { int b2 = blk - 1024; W = W_qkv; BP = wqkv_p; K = 1024; N = 2560; bx = b2 % 80; by = b2 / 80; }
    else                 { int b2 = blk - 3584; W = W_out; BP = wout_p; K = 512;  N = 1024; bx = b2 & 31; by = b2 >> 5; }
    const int n0 = bx * 32, k0 = by * 32;
    const int tx = tid & 31, ty = tid >> 5;
#pragma unroll
    for (int i = 0; i < 4; ++i)
      tile[ty + 8 * i][tx] = W[(size_t)(k0 + ty + 8 * i) * N + n0 + tx];
    __syncthreads();
    if (tid < 128) {
      int cc = tid & 31, kq = tid >> 5;
      int c = n0 + cc, k = k0 + kq * 8;
      bf16x8 v;
#pragma unroll
      for (int i = 0; i < 8; ++i) v[i] = (bf16)tile[kq * 8 + i][cc];
      *(bf16x8*)(BP + ((size_t)(c >> 4) * (K >> 3) + (k >> 3)) * 128 + (c & 15) * 8) = v;
    }
    return;
  }
  blk -= 4096;  // pe_proj
  int idx = blk * 256 + tid;
  int n = idx >> 10, c = idx & 1023;
  float s = 0.f;
#pragma unroll
  for (int e = 0; e < 32; ++e)
    s += pe[n * 32 + e] * W_pos[(size_t)(1024 + e) * 1024 + c];
  pe_pj[idx] = (bf16)s;
}

// ---------------- bf16 MFMA GEMM, B-direct, m97 geometry: 128x128 tile, 256 thr
// = 4 waves (2x2), wave tile 64x64. A: 3-buffer LDS ring (48KB -> 3 blocks/CU),
// gld_lds lead-2, counted vmcnt(4) + one barrier per tile. B: fragment-packed
// global, straight to registers from L2. Row-major XCD chunking (r11 proven).
template <int NT, int OUT_BF16>
__global__ __launch_bounds__(256, 3) void gemm_bd(
    const bf16* __restrict__ A, const bf16* __restrict__ BP, void* __restrict__ Cout,
    int M, int N, int K,
    const float* __restrict__ bias, const bf16* __restrict__ add_full,
    const bf16* __restrict__ add_mod) {
  __shared__ __align__(16) bf16 As[3][128 * 64];  // 16KB per buffer
  const int tid = threadIdx.x;
  const int wave = tid >> 6, lane = tid & 63;
  const int wr = wave >> 1, wc = wave & 1;
  const int lr = lane & 15, lg = lane >> 4;
  const int KB = K >> 3;

  const int nwg = gridDim.x * gridDim.y;
  const int bid = blockIdx.y * gridDim.x + blockIdx.x;
  const int s = (bid & 7) * (nwg >> 3) + (bid >> 3);
  const int row0 = (s / gridDim.x) * 128, col0 = (s % gridDim.x) * 128;
  const int cb0 = (col0 >> 4) + wc * 4;

  // A staging (rule 21: linear LDS dest, inverse-swizzled source); 4 chunks of 32 rows
  const int trow = tid >> 3;
  const int cbd = ((tid & 7) * 16) ^ ((trow & 7) << 4);
  const bf16* asrc = A + (size_t)(row0 + trow) * K + (cbd >> 1);
  f32x4 acc[4][4] = {};

  auto STAGE = [&](int sel, int t) {
    char* al = (char*)&As[sel][0] + tid * 16;
#pragma unroll
    for (int c = 0; c < 4; ++c)
      gld_lds16(asrc + (size_t)c * 32 * K + t * 64, al + c * 4096);
  };

  STAGE(0, 0);
  STAGE(1, 1);
  asm volatile("s_waitcnt vmcnt(4)" ::: "memory");  // tile0 landed, tile1 in flight
  __builtin_amdgcn_s_barrier();

#pragma unroll
  for (int t = 0; t < NT; ++t) {
    if (t + 2 < NT) STAGE((t + 2) % 3, t + 2);
    const char* Ab = (const char*)&As[t % 3][0];
#pragma unroll
    for (int kc = 0; kc < 2; ++kc) {
      const int kb = (t << 3) + kc * 4 + lg;
      bf16x8 bfr[4], af[4];
#pragma unroll
      for (int nt = 0; nt < 4; ++nt)
        bfr[nt] = *(const bf16x8*)(BP + ((size_t)(cb0 + nt) * KB + kb) * 128 + lr * 8);
#pragma unroll
      for (int mt = 0; mt < 4; ++mt) {
        int r = wr * 64 + mt * 16 + lr;
        af[mt] = *(const bf16x8*)(Ab + r * 128 + ((kc * 64 + lg * 16) ^ ((r & 7) << 4)));
      }
      __builtin_amdgcn_s_setprio(1);
#pragma unroll
      for (int mt = 0; mt < 4; ++mt)
#pragma unroll
        for (int nt = 0; nt < 4; ++nt)
          acc[mt][nt] = MFMA16(af[mt], bfr[nt], acc[mt][nt]);
      __builtin_amdgcn_s_setprio(0);
    }
    if (t + 2 < NT)
      asm volatile("s_waitcnt vmcnt(4)" ::: "memory");  // t+1 landed, t+2 in flight
    else
      asm volatile("s_waitcnt vmcnt(0)" ::: "memory");
    __builtin_amdgcn_s_barrier();
  }

#pragma unroll
  for (int mt = 0; mt < 4; ++mt) {
#pragma unroll
    for (int v = 0; v < 4; ++v) {
      int r = row0 + wr * 64 + mt * 16 + lg * 4 + v;
#pragma unroll
      for (int nt = 0; nt < 4; ++nt) {
        int c = col0 + wc * 64 + nt * 16 + lr;
        float val = acc[mt][nt][v];
        if (bias) val += bias[c];
        if (add_full) val += (float)add_full[(size_t)r * N + c];
        if (add_mod) val += (float)add_mod[(size_t)(r & 1023) * N + c];
        if (OUT_BF16)
          ((bf16*)Cout)[(size_t)r * N + c] = (bf16)val;
        else
          ((float*)Cout)[(size_t)r * N + c] = val;
      }
    }
  }
}

// ---------------- FeatureNorm over sequence dim; h bf16 in, hn bf16 out
__global__ __launch_bounds__(512) void featnorm_kernel(const bf16* __restrict__ h,
                                                       bf16* __restrict__ hn,
                                                       const float* __restrict__ gamma,
                                                       const float* __restrict__ beta) {
  const int b = blockIdx.x >> 4;
  const int d0 = (blockIdx.x & 15) << 6;
  const int tid = threadIdx.x;
  const int c = tid & 63, g = tid >> 6;
  const size_t base = (size_t)b * (1024 * 1024) + d0 + c;
  float s = 0.f, s2 = 0.f;
  for (int n = g * 128; n < g * 128 + 128; ++n) {
    float v = (float)h[base + (size_t)n * 1024];
    s += v; s2 += v * v;
  }
  __shared__ float rs[8][64], rs2[8][64];
  rs[g][c] = s; rs2[g][c] = s2;
  __syncthreads();
  __shared__ float smean[64], srstd[64];
  if (tid < 64) {
    float S = 0.f, S2 = 0.f;
#pragma unroll
    for (int q = 0; q < 8; ++q) { S += rs[q][tid]; S2 += rs2[q][tid]; }
    float mean = S * (1.f / 1024.f);
    float var = S2 * (1.f / 1024.f) - mean * mean;
    smean[tid] = mean;
    srstd[tid] = rsqrtf(var + 1e-5f);
  }
  __syncthreads();
  const float mean = smean[c], rstd = srstd[c];
  const float gm = gamma[d0 + c], bt = beta[d0 + c];
  for (int n = g * 128; n < g * 128 + 128; ++n) {
    size_t idx = base + (size_t)n * 1024;
    hn[idx] = (bf16)(gm * ((float)h[idx] - mean) * rstd + bt);
  }
}

// ---------------- fused sk (log2-domain k norms) + vtrans
__global__ __launch_bounds__(256) void skvt_kernel(const bf16* __restrict__ qkv,
                                                   const float* __restrict__ scale_ptr,
                                                   float* __restrict__ skl,
                                                   bf16* __restrict__ vT) {
  const int tid = threadIdx.x;
  if (blockIdx.x < 4096) {
    const int lr = tid & 15;
    const int task = blockIdx.x * 16 + (tid >> 4);
    const int bh = task >> 10, n = task & 1023;
    const int b = bh >> 3, h = bh & 7;
    const bf16x8 v = *(const bf16x8*)(qkv + (size_t)(b * 1024 + n) * 2560 +
                                      1024 + h * 128 + lr * 8);
    float s = 0.f;
#pragma unroll
    for (int i = 0; i < 8; ++i) { float f = (float)v[i]; s += f * f; }
#pragma unroll
    for (int off = 1; off < 16; off <<= 1) s += __shfl_xor(s, off);
    if (lr == 0) {
      float sc = scale_ptr[0];
      skl[task] = s * (1.44269504f / (sc * sc));
    }
    return;
  }
  __shared__ bf16 tile[32][34];
  const int blk = blockIdx.x - 4096;
  const int b = blk >> 9;
  const int rem = blk & 511;
  const int c0 = (rem >> 5) * 32, n0 = (rem & 31) * 32;
  const int tx = tid & 31, ty = tid >> 5;
#pragma unroll
  for (int i = 0; i < 4; ++i)
    tile[ty + 8 * i][tx] = qkv[(size_t)(b * 1024 + n0 + ty + 8 * i) * 2560 + 2048 + c0 + tx];
  __syncthreads();
#pragma unroll
  for (int i = 0; i < 4; ++i)
    vT[(size_t)(b * 512 + c0 + ty + 8 * i) * 1024 + n0 + tx] = tile[tx][ty + 8 * i];
}

// ---------------- MFMA distance attention, QBLK=128 (8 waves, 512 thr).
// r11 2-buffer version (68KB LDS -> 2 blocks/CU; cross-block overlap hides drains).
__global__ __launch_bounds__(512, 4) void attn_mfma(const bf16* __restrict__ qkv,
                                                    const bf16* __restrict__ vT,
                                                    const float* __restrict__ skl,
                                                    const float* __restrict__ scale_ptr,
                                                    bf16* __restrict__ attn_o) {
  const int swz = ((blockIdx.x & 7) << 6) + (blockIdx.x >> 3);
  const int it = swz & 7, bh = swz >> 3;
  const int b = bh >> 3, h = bh & 7;
  const int i0 = it * 128;
  const int tid = threadIdx.x, wave = tid >> 6, lane = tid & 63;
  const int lr = lane & 15, lg = lane >> 4;
  const float sc = scale_ptr[0];
  const float c2 = 2.f * 1.44269504f / (sc * sc);

  __shared__ __align__(16) bf16 Ks[2][64 * 128];
  __shared__ __align__(16) bf16 Vs[2][64 * 64];
  __shared__ __align__(16) bf16 Ps[8][16 * 64];
  __shared__ float sks[1024];

  const int trowK = tid >> 4;
  const int cbKd = ((tid & 15) * 16) ^ ((trowK & 7) << 4);
  const bf16* ksrc = qkv + (size_t)(b * 1024 + trowK) * 2560 + 1024 + h * 128 + (cbKd >> 1);
  const int trowV = tid >> 3;
  const int cbVd = ((tid & 7) * 16) ^ ((trowV & 7) << 4);
  const bf16* vsrc = vT + (size_t)(b * 512 + h * 64 + trowV) * 1024 + (cbVd >> 1);

  auto STAGE = [&](int sel, int jt) {
    const bf16* kp = ksrc + (size_t)jt * 64 * 2560;
    char* kl = (char*)&Ks[sel][0] + tid * 16;
    gld_lds16(kp, kl);
    gld_lds16(kp + (size_t)32 * 2560, kl + 8192);
    gld_lds16(vsrc + jt * 64, (char*)&Vs[sel][0] + tid * 16);
  };

  {
    float2 sv = ((const float2*)(skl + (size_t)bh * 1024))[tid];
    *(float2*)&sks[tid * 2] = sv;
  }
  bf16x8 qf[4];
  {
    const bf16* qrow = qkv + (size_t)(b * 1024 + i0 + wave * 16 + lr) * 2560 + h * 128;
#pragma unroll
    for (int kc = 0; kc < 4; ++kc) qf[kc] = *(const bf16x8*)(qrow + kc * 32 + lg * 8);
  }
  __syncthreads();

  bf16x8 vones;
  {
    bf16 one_or_zero = (lr == 0) ? (bf16)1.0f : (bf16)0.0f;
#pragma unroll
    for (int i = 0; i < 8; ++i) vones[i] = one_or_zero;
  }

  f32x4 o[4] = {};
  f32x4 o_l = {};

  STAGE(0, 0);
  asm volatile("s_waitcnt vmcnt(0)" ::: "memory");
  __builtin_amdgcn_s_barrier();

#pragma unroll
  for (int jt = 0; jt < 16; ++jt) {
    const int cur = jt & 1;
    if (jt < 15) STAGE(cur ^ 1, jt + 1);

    f32x4 sacc[4] = {};
    __builtin_amdgcn_s_setprio(1);
#pragma unroll
    for (int kc = 0; kc < 4; ++kc) {
#pragma unroll
      for (int nt = 0; nt < 4; ++nt) {
        int j = nt * 16 + lr;
        int byte = j * 256 + (((kc * 32 + lg * 8) * 2) ^ ((j & 7) << 4));
        bf16x8 kf = *(const bf16x8*)((const char*)&Ks[cur][0] + byte);
        sacc[nt] = MFMA16(qf[kc], kf, sacc[nt]);
      }
    }
    __builtin_amdgcn_s_setprio(0);

#pragma unroll
    for (int nt = 0; nt < 4; ++nt) {
      float skv = sks[jt * 64 + nt * 16 + lr];
#pragma unroll
      for (int v = 0; v < 4; ++v) {
        float p = __builtin_amdgcn_exp2f(sacc[nt][v] * c2 - skv);
        int r = lg * 4 + v, c = nt * 16 + lr;
        int byte = r * 128 + ((c * 2) ^ ((r & 7) << 4));
        *(bf16*)((char*)&Ps[wave][0] + byte) = (bf16)p;
      }
    }
    bf16x8 pf[2];
#pragma unroll
    for (int kc = 0; kc < 2; ++kc) {
      int byte = lr * 128 + (((kc * 32 + lg * 8) * 2) ^ ((lr & 7) << 4));
      pf[kc] = *(const bf16x8*)((const char*)&Ps[wave][0] + byte);
    }
    __builtin_amdgcn_s_setprio(1);
#pragma unroll
    for (int kc = 0; kc < 2; ++kc) {
#pragma unroll
      for (int nt = 0; nt < 4; ++nt) {
        int d = nt * 16 + lr;
        int byte = d * 128 + (((kc * 32 + lg * 8) * 2) ^ ((d & 7) << 4));
        bf16x8 vf = *(const bf16x8*)((const char*)&Vs[cur][0] + byte);
        o[nt] = MFMA16(pf[kc], vf, o[nt]);
      }
      o_l = MFMA16(pf[kc], vones, o_l);
    }
    __builtin_amdgcn_s_setprio(0);

    asm volatile("s_waitcnt vmcnt(0)" ::: "memory");
    __builtin_amdgcn_s_barrier();
  }

#pragma unroll
  for (int v = 0; v < 4; ++v) {
    float ls = __shfl(o_l[v], lg << 4);
    float inv = 1.f / ls;
    int r = i0 + wave * 16 + lg * 4 + v;
#pragma unroll
    for (int nt = 0; nt < 4; ++nt) {
      int c = h * 64 + nt * 16 + lr;
      attn_o[(size_t)(b * 1024 + r) * 512 + c] = (bf16)(o[nt][v] * inv);
    }
  }
}

extern "C" void kernel_launch(void* const* d_in, const int* in_sizes, int n_in,
                              void* d_out, int out_size, void* d_ws, size_t ws_size,
                              hipStream_t stream) {
  const float* x     = (const float*)d_in[0];
  const float* gamma = (const float*)d_in[1];
  const float* beta  = (const float*)d_in[2];
  const float* pe    = (const float*)d_in[3];
  const float* W_pos = (const float*)d_in[4];
  const float* b_pos = (const float*)d_in[5];
  const float* W_qkv = (const float*)d_in[6];
  const float* b_qkv = (const float*)d_in[7];
  const float* W_out = (const float*)d_in[8];
  const float* b_out = (const float*)d_in[9];
  const float* scale = (const float*)d_in[10];
  float* outp = (float*)d_out;

  char* ws = (char*)d_ws;
  const size_t MB = 1 << 20;
  bf16* x_bf   = (bf16*)(ws);            // 16MB, persists to GEMM3 (bf16 residual)
  bf16* wpos_p = (bf16*)(ws + 16 * MB);  // 2MB  (fragment-packed)
  bf16* wqkv_p = (bf16*)(ws + 18 * MB);  // 5MB  (fragment-packed)
  bf16* wout_p = (bf16*)(ws + 23 * MB);  // 1MB  (fragment-packed)
  bf16* pe_pj  = (bf16*)(ws + 24 * MB);  // 2MB (dead after GEMM1)
  bf16* vT     = (bf16*)(ws + 24 * MB);  // 8MB (aliases pe_pj region)
  bf16* h      = (bf16*)(ws + 32 * MB);  // 16MB (dead after featnorm)
  bf16* attn_o = (bf16*)(ws + 32 * MB);  // 8MB (aliases h)
  bf16* qkv    = (bf16*)(ws + 48 * MB);  // 40MB
  float* skl   = (float*)(ws + 88 * MB); // 256KB
  bf16* hn     = (bf16*)(ws + 96 * MB);  // 16MB

  prep_kernel<<<12288, 256, 0, stream>>>(x, W_pos, W_qkv, W_out, pe,
                                         x_bf, wpos_p, wqkv_p, wout_p, pe_pj);
  // h = x + x@W_pos + pe_pj + b_pos   (bf16 out, bf16 residual) — 512 blocks
  gemm_bd<16, 1><<<dim3(8, 64), 256, 0, stream>>>(x_bf, wpos_p, h, 8192, 1024, 1024,
                                                  b_pos, x_bf, pe_pj);
  featnorm_kernel<<<128, 512, 0, stream>>>(h, hn, gamma, beta);
  // qkv = hn @ W_qkv + b_qkv  (bf16 out) — 1280 blocks
  gemm_bd<16, 1><<<dim3(20, 64), 256, 0, stream>>>(hn, wqkv_p, qkv, 8192, 2560, 1024,
                                                   b_qkv, nullptr, nullptr);
  skvt_kernel<<<8192, 256, 0, stream>>>(qkv, scale, skl, vT);
  attn_mfma<<<512, 512, 0, stream>>>(qkv, vT, skl, scale, attn_o);
  // out = x + attn_o @ W_out + b_out  (fp32 out, bf16 residual) — 512 blocks
  gemm_bd<8, 0><<<dim3(8, 64), 256, 0, stream>>>(attn_o, wout_p, outp, 8192, 1024, 512,
                                                 b_out, x_bf, nullptr);
}